// Round 6
// baseline (584.231 us; speedup 1.0000x reference)
//
#include <hip/hip_runtime.h>

typedef unsigned short ushort_t;
typedef unsigned int uint_t;

typedef short bf16x8 __attribute__((ext_vector_type(8)));
typedef float f32x4 __attribute__((ext_vector_type(4)));
typedef uint_t uint4v __attribute__((ext_vector_type(4)));

#define DIM 128
#define BSHIFT 8
#define BNODES 256           // nodes per bucket (1<<BSHIFT)
#define NCHUNK 8             // feature chunks (16 feats each), chunk-major layout

__device__ __forceinline__ float bf2f(ushort_t u) {
    uint_t x = ((uint_t)u) << 16;
    float f;
    __builtin_memcpy(&f, &x, 4);
    return f;
}

__device__ __forceinline__ ushort_t f2bf(float f) {
    uint_t x;
    __builtin_memcpy(&x, &f, 4);
    uint_t r = (x + 0x7fffu + ((x >> 16) & 1u)) >> 16;
    return (ushort_t)r;
}

// ---------- conversion: x (row-major f32) -> xb (chunk-major bf16 [8][N][16]) ----------

__global__ __launch_bounds__(256) void k_cvt_chunk(const float* __restrict__ in,
                                                   ushort_t* __restrict__ out, int N) {
    int i = blockIdx.x * blockDim.x + threadIdx.x;   // N*16 units of 8 feats
    if (i >= N * 16) return;
    int node = i >> 4, q = i & 15;
    const float4* p = (const float4*)(in + (size_t)node * DIM + q * 8);
    float4 f0 = p[0], f1 = p[1];
    uint4v o;
    o.x = (uint_t)f2bf(f0.x) | ((uint_t)f2bf(f0.y) << 16);
    o.y = (uint_t)f2bf(f0.z) | ((uint_t)f2bf(f0.w) << 16);
    o.z = (uint_t)f2bf(f1.x) | ((uint_t)f2bf(f1.y) << 16);
    o.w = (uint_t)f2bf(f1.z) | ((uint_t)f2bf(f1.w) << 16);
    size_t CS = (size_t)N * 16;
    *(uint4v*)(out + (size_t)(q >> 1) * CS + (size_t)node * 16 + (q & 1) * 8) = o;
}

// all four weight transposes in one launch: WT[n*128+k] = bf16(W[k*128+n])
__global__ void k_wt4(const float* __restrict__ W0, const float* __restrict__ W1,
                      const float* __restrict__ W2, const float* __restrict__ W3,
                      ushort_t* __restrict__ T0, ushort_t* __restrict__ T1,
                      ushort_t* __restrict__ T2, ushort_t* __restrict__ T3) {
    int i = blockIdx.x * blockDim.x + threadIdx.x;  // 4*16384
    int w = i >> 14, j = i & 16383;
    int n = j >> 7, k = j & 127;
    const float* W = (w == 0) ? W0 : (w == 1) ? W1 : (w == 2) ? W2 : W3;
    ushort_t* T = (w == 0) ? T0 : (w == 1) ? T1 : (w == 2) ? T2 : T3;
    T[j] = f2bf(W[k * DIM + n]);
}

// ---------- CSR build via two-level bucket counting sort ----------
// Device-scope atomics execute at the coherence point on 8-XCD parts and cap
// at ~13 G ops/s; LDS histograms + ~0.2M global reservations avoid that tax.

__global__ __launch_bounds__(256) void k_bhist(const int* __restrict__ dst, int E, int NB,
                                               int* __restrict__ bucketCount) {
    __shared__ int hist[512];
    int t = threadIdx.x;
    for (int b = t; b < NB; b += 256) hist[b] = 0;
    __syncthreads();
    int per = (E + gridDim.x - 1) / gridDim.x;
    int beg = blockIdx.x * per, end = min(beg + per, E);
    for (int i = beg + t; i < end; i += 256)
        atomicAdd(&hist[dst[i] >> BSHIFT], 1);
    __syncthreads();
    for (int b = t; b < NB; b += 256) {
        int v = hist[b];
        if (v) atomicAdd(&bucketCount[b], v);
    }
}

__global__ __launch_bounds__(512) void k_bscan(const int* __restrict__ bucketCount, int NB, int E,
                                               int* __restrict__ bucketBase,
                                               int* __restrict__ bucketCursor,
                                               int* __restrict__ row_ptr, int N) {
    __shared__ int lds[512];
    int t = threadIdx.x;
    int v = (t < NB) ? bucketCount[t] : 0;
    lds[t] = v;
    __syncthreads();
    for (int off = 1; off < 512; off <<= 1) {
        int u = (t >= off) ? lds[t - off] : 0;
        __syncthreads();
        lds[t] += u;
        __syncthreads();
    }
    if (t < NB) {
        int b = lds[t] - v;
        bucketBase[t] = b;
        bucketCursor[t] = b;
    }
    if (t == 0) row_ptr[N] = E;
}

__global__ __launch_bounds__(256) void k_bucketize(const int* __restrict__ src,
                                                   const int* __restrict__ dst, int E, int NB,
                                                   int* __restrict__ bucketCursor,
                                                   uint_t* __restrict__ bebuf) {
    __shared__ int hist[512];
    __shared__ int base[512];
    int t = threadIdx.x;
    for (int b = t; b < NB; b += 256) hist[b] = 0;
    __syncthreads();
    int per = (E + gridDim.x - 1) / gridDim.x;
    int beg = blockIdx.x * per, end = min(beg + per, E);
    for (int i = beg + t; i < end; i += 256)
        atomicAdd(&hist[dst[i] >> BSHIFT], 1);
    __syncthreads();
    for (int b = t; b < NB; b += 256) {
        int v = hist[b];
        base[b] = v ? atomicAdd(&bucketCursor[b], v) : 0;
        hist[b] = 0;
    }
    __syncthreads();
    for (int i = beg + t; i < end; i += 256) {
        int d = dst[i], s = src[i];
        int b = d >> BSHIFT;
        int off = atomicAdd(&hist[b], 1);
        bebuf[base[b] + off] = ((uint_t)(d & (BNODES - 1)) << 24) | (uint_t)s;
    }
}

__global__ __launch_bounds__(256) void k_bcsr(const uint_t* __restrict__ bebuf,
                                              const int* __restrict__ bucketBase,
                                              const int* __restrict__ bucketCount, int N,
                                              int* __restrict__ row_ptr, int* __restrict__ csr) {
    __shared__ int hist[BNODES];
    __shared__ int cur[BNODES];
    int t = threadIdx.x;
    int b = blockIdx.x;
    int ebase = bucketBase[b], cnt = bucketCount[b];
    int nodeBase = b << BSHIFT;
    hist[t] = 0;
    __syncthreads();
    for (int i = t; i < cnt; i += 256)
        atomicAdd(&hist[bebuf[ebase + i] >> 24], 1);
    __syncthreads();
    int v = hist[t];
    for (int off = 1; off < 256; off <<= 1) {
        int u = (t >= off) ? hist[t - off] : 0;
        __syncthreads();
        hist[t] += u;
        __syncthreads();
    }
    int excl = hist[t] - v;
    int node = nodeBase + t;
    if (node < N) row_ptr[node] = ebase + excl;
    cur[t] = excl;
    __syncthreads();
    for (int i = t; i < cnt; i += 256) {
        uint_t e = bebuf[ebase + i];
        int dl = (int)(e >> 24);
        int pos = atomicAdd(&cur[dl], 1);
        csr[ebase + pos] = (int)(e & 0xFFFFFFu);
    }
}

// ---------- degree-sorted node permutation (kills wave divergence in k_agg) ----------

__global__ __launch_bounds__(256) void k_dhist(const int* __restrict__ rp, int N,
                                               int* __restrict__ degCount) {
    __shared__ int h[256];
    int t = threadIdx.x;
    h[t] = 0;
    __syncthreads();
    int i = blockIdx.x * 256 + t;
    if (i < N) {
        int d = rp[i + 1] - rp[i];
        atomicAdd(&h[d > 255 ? 255 : d], 1);
    }
    __syncthreads();
    int v = h[t];
    if (v) atomicAdd(&degCount[t], v);
}

__global__ __launch_bounds__(256) void k_dscan(const int* __restrict__ degCount,
                                               int* __restrict__ classBase,
                                               int* __restrict__ classCursor) {
    __shared__ int lds[256];
    int t = threadIdx.x;
    int v = degCount[t];
    lds[t] = v;
    __syncthreads();
    for (int off = 1; off < 256; off <<= 1) {
        int u = (t >= off) ? lds[t - off] : 0;
        __syncthreads();
        lds[t] += u;
        __syncthreads();
    }
    int b = lds[t] - v;
    classBase[t] = b;
    classCursor[t] = b;
}

__global__ __launch_bounds__(256) void k_dscatter(const int* __restrict__ rp, int N,
                                                  int* __restrict__ classCursor,
                                                  int* __restrict__ perm) {
    __shared__ int h[256];
    __shared__ int base[256];
    int t = threadIdx.x;
    h[t] = 0;
    __syncthreads();
    int i = blockIdx.x * 256 + t;
    int cls = 0;
    if (i < N) {
        int d = rp[i + 1] - rp[i];
        cls = d > 255 ? 255 : d;
        atomicAdd(&h[cls], 1);
    }
    __syncthreads();
    int v = h[t];
    base[t] = v ? atomicAdd(&classCursor[t], v) : 0;
    h[t] = 0;
    __syncthreads();
    if (i < N) {
        int r = atomicAdd(&h[cls], 1);
        perm[base[cls] + r] = i;
    }
}

// ---------- mean aggregation, chunk-major + XCD-affine ----------
// chunk = blockIdx%8 -> (round-robin heuristic) all blocks of chunk c land on
// XCD c, whose 3.2 MB table slice stays L2-resident. 2 lanes/node, 32
// nodes/wave; nodes come from the degree-sorted perm so a wave's nodes have
// ~equal degree (no divergence waste). csr is re-streamed 8x -> nt loads so
// the stream doesn't evict the hot table; aggb written with nt stores.

__device__ __forceinline__ void acc8v(float* a, uint4v p) {
    a[0] += bf2f((ushort_t)(p.x & 0xffffu));
    a[1] += bf2f((ushort_t)(p.x >> 16));
    a[2] += bf2f((ushort_t)(p.y & 0xffffu));
    a[3] += bf2f((ushort_t)(p.y >> 16));
    a[4] += bf2f((ushort_t)(p.z & 0xffffu));
    a[5] += bf2f((ushort_t)(p.z >> 16));
    a[6] += bf2f((ushort_t)(p.w & 0xffffu));
    a[7] += bf2f((ushort_t)(p.w >> 16));
}

__global__ __launch_bounds__(256) void k_agg_c(const ushort_t* __restrict__ X,
                                               const int* __restrict__ rp,
                                               const int* __restrict__ csr,
                                               const int* __restrict__ perm,
                                               ushort_t* __restrict__ out, int N) {
    int chunk = blockIdx.x & 7;
    int g = blockIdx.x >> 3;
    int t = threadIdx.x;
    int idx = g * 128 + (t >> 1);
    if (idx >= N) return;
    int node = perm[idx];
    int half = t & 1;
    size_t CS = (size_t)N * 16;
    const ushort_t* Xc = X + (size_t)chunk * CS;

    int beg = __builtin_nontemporal_load(rp + node);
    int end = __builtin_nontemporal_load(rp + node + 1);
    float a[8] = {0.f, 0.f, 0.f, 0.f, 0.f, 0.f, 0.f, 0.f};

    int e = beg;
    for (; e + 4 <= end; e += 4) {
        int s0 = __builtin_nontemporal_load(csr + e + 0);
        int s1 = __builtin_nontemporal_load(csr + e + 1);
        int s2 = __builtin_nontemporal_load(csr + e + 2);
        int s3 = __builtin_nontemporal_load(csr + e + 3);
        uint4v p0 = *(const uint4v*)(Xc + (size_t)s0 * 16 + half * 8);
        uint4v p1 = *(const uint4v*)(Xc + (size_t)s1 * 16 + half * 8);
        uint4v p2 = *(const uint4v*)(Xc + (size_t)s2 * 16 + half * 8);
        uint4v p3 = *(const uint4v*)(Xc + (size_t)s3 * 16 + half * 8);
        acc8v(a, p0); acc8v(a, p1); acc8v(a, p2); acc8v(a, p3);
    }
    for (; e < end; e++) {
        int s = __builtin_nontemporal_load(csr + e);
        uint4v p = *(const uint4v*)(Xc + (size_t)s * 16 + half * 8);
        acc8v(a, p);
    }

    int cnt = end - beg;
    float sc = (cnt > 0) ? 1.f / (float)cnt : 0.f;
    uint4v o;
    o.x = (uint_t)f2bf(a[0] * sc) | ((uint_t)f2bf(a[1] * sc) << 16);
    o.y = (uint_t)f2bf(a[2] * sc) | ((uint_t)f2bf(a[3] * sc) << 16);
    o.z = (uint_t)f2bf(a[4] * sc) | ((uint_t)f2bf(a[5] * sc) << 16);
    o.w = (uint_t)f2bf(a[6] * sc) | ((uint_t)f2bf(a[7] * sc) << 16);
    __builtin_nontemporal_store(o, (uint4v*)(out + (size_t)chunk * CS + (size_t)node * 16 + half * 8));
}

// ---------- fused GEMM with LDS-staged weights, chunk-major A ----------
// out = A1*W_l + A2*W_r + b; 32 rows/wave, 128 rows/block (4 waves).
// A1/A2 are chunk-major [8][M][16]; feature f lives at (f>>4)*CS + m*16 + (f&15).
// MFMA 16x16x32 bf16 layouts (m89-verified):
//   A frag: lane holds A[m=lane&15][k=quad*8+j]
//   B frag: lane holds B[k=quad*8+j][n=lane&15] = WT[n=lane&15][k=quad*8+j]
//   C/D   : col=lane&15, row=quad*4+reg

template <bool RELU, bool OUT_BF16>
__global__ __launch_bounds__(256) void k_gemm(const ushort_t* __restrict__ A1,
                                              const ushort_t* __restrict__ A2,
                                              const ushort_t* __restrict__ WTl,
                                              const ushort_t* __restrict__ WTr,
                                              const float* __restrict__ bias,
                                              void* __restrict__ Out, int n_waves, int M) {
    __shared__ ushort_t sW[2 * 128 * 128];   // 64 KB
    int t = threadIdx.x;
    int wave = (int)((blockIdx.x * 256u + t) >> 6);
    int lane = t & 63;
    int col = lane & 15;
    int quad = lane >> 4;
    bool active = (wave < n_waves);
    size_t CS = (size_t)M * 16;

    // A-fragment loads issued first: their latency overlaps staging + barrier.
    bf16x8 a[2][8];
    if (active) {
#pragma unroll
        for (int tt = 0; tt < 2; tt++) {
            int arow = wave * 32 + tt * 16 + col;
            size_t rbase = (size_t)arow * 16 + (quad & 1) * 8;
            size_t cbase = (size_t)(quad >> 1) * CS;
#pragma unroll
            for (int ks = 0; ks < 4; ks++)
                a[tt][ks] = *(const bf16x8*)(A1 + cbase + (size_t)(ks * 2) * CS + rbase);
#pragma unroll
            for (int ks = 0; ks < 4; ks++)
                a[tt][4 + ks] = *(const bf16x8*)(A2 + cbase + (size_t)(ks * 2) * CS + rbase);
        }
    }

    // stage weights: thread t copies one row (t>>7 selects table, t&127 the row)
    {
        int tab = t >> 7, row = t & 127;
        const ushort_t* g = (tab ? WTr : WTl) + (size_t)row * 128;
        ushort_t* d = sW + (size_t)t * 128;
        int sw = row & 15;
#pragma unroll
        for (int c = 0; c < 16; c++) {
            uint4 v = *(const uint4*)(g + c * 8);
            *(uint4*)(d + ((c ^ sw) * 8)) = v;
        }
    }
    __syncthreads();
    if (!active) return;

    f32x4 acc[2][8];
#pragma unroll
    for (int tt = 0; tt < 2; tt++)
#pragma unroll
        for (int nt = 0; nt < 8; nt++) acc[tt][nt] = (f32x4){0.f, 0.f, 0.f, 0.f};

    const ushort_t* sWl = sW;
    const ushort_t* sWr = sW + 128 * 128;
#pragma unroll
    for (int nt = 0; nt < 8; nt++) {
        int row = nt * 16 + col;
        const ushort_t* bl = sWl + (size_t)row * 128;
        const ushort_t* br = sWr + (size_t)row * 128;
#pragma unroll
        for (int ks = 0; ks < 4; ks++) {
            bf16x8 b = *(const bf16x8*)(bl + (((ks * 4 + quad) ^ col) * 8));
            acc[0][nt] = __builtin_amdgcn_mfma_f32_16x16x32_bf16(a[0][ks], b, acc[0][nt], 0, 0, 0);
            acc[1][nt] = __builtin_amdgcn_mfma_f32_16x16x32_bf16(a[1][ks], b, acc[1][nt], 0, 0, 0);
        }
#pragma unroll
        for (int ks = 0; ks < 4; ks++) {
            bf16x8 b = *(const bf16x8*)(br + (((ks * 4 + quad) ^ col) * 8));
            acc[0][nt] = __builtin_amdgcn_mfma_f32_16x16x32_bf16(a[0][4 + ks], b, acc[0][nt], 0, 0, 0);
            acc[1][nt] = __builtin_amdgcn_mfma_f32_16x16x32_bf16(a[1][4 + ks], b, acc[1][nt], 0, 0, 0);
        }
    }

#pragma unroll
    for (int tt = 0; tt < 2; tt++)
#pragma unroll
        for (int nt = 0; nt < 8; nt++) {
            int c = nt * 16 + col;
            float bv = bias[c];
#pragma unroll
            for (int r = 0; r < 4; r++) {
                int m = wave * 32 + tt * 16 + quad * 4 + r;
                if (m < M) {
                    float v = acc[tt][nt][r] + bv;
                    if (RELU) v = v > 0.f ? v : 0.f;
                    if (OUT_BF16)
                        ((ushort_t*)Out)[(size_t)nt * CS + (size_t)m * 16 + col] = f2bf(v);
                    else
                        ((float*)Out)[(size_t)m * DIM + c] = v;
                }
            }
        }
}

// ---------- host ----------

extern "C" void kernel_launch(void* const* d_in, const int* in_sizes, int n_in,
                              void* d_out, int out_size, void* d_ws, size_t ws_size,
                              hipStream_t stream) {
    const int N = in_sizes[0] / DIM;   // 100000
    const int E = in_sizes[1] / 2;     // 1600000
    const int NB = (N + BNODES - 1) >> BSHIFT;   // 391 buckets

    const float* x   = (const float*)d_in[0];
    const int*   ei  = (const int*)d_in[1];
    const int*   src = ei;
    const int*   dst = ei + E;
    const float* W1l = (const float*)d_in[2];
    const float* b1  = (const float*)d_in[3];
    const float* W1r = (const float*)d_in[4];
    const float* W2l = (const float*)d_in[5];
    const float* b2  = (const float*)d_in[6];
    const float* W2r = (const float*)d_in[7];
    float* out = (float*)d_out;

    char* ws = (char*)d_ws;
    size_t off = 0;
    auto alloc = [&](size_t bytes) -> char* {
        char* p = ws + off;
        off = (off + bytes + 255) & ~(size_t)255;
        return p;
    };

    int*      bucketCount  = (int*)alloc((size_t)NB * 4);
    int*      bucketBase   = (int*)alloc((size_t)NB * 4);
    int*      bucketCursor = (int*)alloc((size_t)NB * 4);
    int*      degCount     = (int*)alloc(256 * 4);
    int*      classBase    = (int*)alloc(256 * 4);
    int*      classCursor  = (int*)alloc(256 * 4);
    int*      perm         = (int*)alloc((size_t)N * 4);
    int*      row_ptr      = (int*)alloc((size_t)(N + 1) * 4);
    int*      csr          = (int*)alloc((size_t)E * 4);
    uint_t*   bebuf        = (uint_t*)alloc((size_t)E * 4);
    ushort_t* xb           = (ushort_t*)alloc((size_t)N * DIM * 2);
    ushort_t* hb           = (ushort_t*)alloc((size_t)N * DIM * 2);
    ushort_t* aggb         = (ushort_t*)alloc((size_t)N * DIM * 2);
    ushort_t* wt1l         = (ushort_t*)alloc((size_t)DIM * DIM * 2);
    ushort_t* wt1r         = (ushort_t*)alloc((size_t)DIM * DIM * 2);
    ushort_t* wt2l         = (ushort_t*)alloc((size_t)DIM * DIM * 2);
    ushort_t* wt2r         = (ushort_t*)alloc((size_t)DIM * DIM * 2);

    // zero histograms (ws is poisoned each call)
    hipMemsetAsync(bucketCount, 0, (size_t)NB * 4, stream);
    hipMemsetAsync(degCount, 0, 256 * 4, stream);

    // x -> bf16 chunk-major
    k_cvt_chunk<<<dim3((N * 16 + 255) / 256), dim3(256), 0, stream>>>(x, xb, N);
    // weights -> transposed bf16 (single launch)
    k_wt4<<<dim3(4 * DIM * DIM / 256), dim3(256), 0, stream>>>(W1l, W1r, W2l, W2r,
                                                               wt1l, wt1r, wt2l, wt2r);
    // CSR build: bucket counting sort
    k_bhist<<<dim3(256), dim3(256), 0, stream>>>(dst, E, NB, bucketCount);
    k_bscan<<<dim3(1), dim3(512), 0, stream>>>(bucketCount, NB, E, bucketBase, bucketCursor, row_ptr, N);
    k_bucketize<<<dim3(256), dim3(256), 0, stream>>>(src, dst, E, NB, bucketCursor, bebuf);
    k_bcsr<<<dim3(NB), dim3(256), 0, stream>>>(bebuf, bucketBase, bucketCount, N, row_ptr, csr);
    // degree-sorted permutation
    {
        int nblk = (N + 255) / 256;
        k_dhist<<<dim3(nblk), dim3(256), 0, stream>>>(row_ptr, N, degCount);
        k_dscan<<<dim3(1), dim3(256), 0, stream>>>(degCount, classBase, classCursor);
        k_dscatter<<<dim3(nblk), dim3(256), 0, stream>>>(row_ptr, N, classCursor, perm);
    }

    const int n_waves = (N + 31) / 32;                          // 3125 (32 rows/wave)
    dim3 gemm_grid((n_waves + 3) / 4), gemm_blk(256);
    const int ngrp = (N + 127) / 128;                           // 128 nodes per block
    dim3 agg_grid(ngrp * NCHUNK), agg_blk(256);                 // chunk = blockIdx%8 (XCD affine)

    // layer 1
    k_agg_c<<<agg_grid, agg_blk, 0, stream>>>(xb, row_ptr, csr, perm, aggb, N);
    k_gemm<true, true><<<gemm_grid, gemm_blk, 0, stream>>>(aggb, xb, wt1l, wt1r, b1, hb, n_waves, N);
    // layer 2
    k_agg_c<<<agg_grid, agg_blk, 0, stream>>>(hb, row_ptr, csr, perm, aggb, N);
    k_gemm<false, false><<<gemm_grid, gemm_blk, 0, stream>>>(aggb, hb, wt2l, wt2r, b2, out, n_waves, N);

    (void)n_in; (void)out_size; (void)ws_size;
}

// Round 7
// 376.015 us; speedup vs baseline: 1.5537x; 1.5537x over previous
//
#include <hip/hip_runtime.h>

typedef unsigned short ushort_t;
typedef unsigned int uint_t;

typedef short bf16x8 __attribute__((ext_vector_type(8)));
typedef float f32x4 __attribute__((ext_vector_type(4)));

#define DIM 128
#define BSHIFT 8
#define BNODES 256           // nodes per bucket (1<<BSHIFT)

__device__ __forceinline__ float bf2f(ushort_t u) {
    uint_t x = ((uint_t)u) << 16;
    float f;
    __builtin_memcpy(&f, &x, 4);
    return f;
}

__device__ __forceinline__ ushort_t f2bf(float f) {
    uint_t x;
    __builtin_memcpy(&x, &f, 4);
    uint_t r = (x + 0x7fffu + ((x >> 16) & 1u)) >> 16;
    return (ushort_t)r;
}

// ---------- conversion kernels ----------

__global__ void k_cvt_f32_bf16(const float* __restrict__ in, ushort_t* __restrict__ out, int n4) {
    int i = blockIdx.x * blockDim.x + threadIdx.x;
    if (i < n4) {
        float4 f = ((const float4*)in)[i];
        ushort4 u;
        u.x = f2bf(f.x); u.y = f2bf(f.y); u.z = f2bf(f.z); u.w = f2bf(f.w);
        ((ushort4*)out)[i] = u;
    }
}

// all four weight transposes in one launch: WT[n*128+k] = bf16(W[k*128+n])
__global__ void k_wt4(const float* __restrict__ W0, const float* __restrict__ W1,
                      const float* __restrict__ W2, const float* __restrict__ W3,
                      ushort_t* __restrict__ T0, ushort_t* __restrict__ T1,
                      ushort_t* __restrict__ T2, ushort_t* __restrict__ T3) {
    int i = blockIdx.x * blockDim.x + threadIdx.x;  // 4*16384
    int w = i >> 14, j = i & 16383;
    int n = j >> 7, k = j & 127;
    const float* W = (w == 0) ? W0 : (w == 1) ? W1 : (w == 2) ? W2 : W3;
    ushort_t* T = (w == 0) ? T0 : (w == 1) ? T1 : (w == 2) ? T2 : T3;
    T[j] = f2bf(W[k * DIM + n]);
}

// ---------- CSR build via two-level bucket counting sort ----------
// Device-scope atomics execute at the coherence point on 8-XCD parts and cap
// at ~13 G ops/s; LDS histograms + ~0.2M global reservations avoid that tax.

__global__ __launch_bounds__(256) void k_bhist(const int* __restrict__ dst, int E, int NB,
                                               int* __restrict__ bucketCount) {
    __shared__ int hist[512];
    int t = threadIdx.x;
    for (int b = t; b < NB; b += 256) hist[b] = 0;
    __syncthreads();
    int per = (E + gridDim.x - 1) / gridDim.x;
    int beg = blockIdx.x * per, end = min(beg + per, E);
    for (int i = beg + t; i < end; i += 256)
        atomicAdd(&hist[dst[i] >> BSHIFT], 1);
    __syncthreads();
    for (int b = t; b < NB; b += 256) {
        int v = hist[b];
        if (v) atomicAdd(&bucketCount[b], v);
    }
}

__global__ __launch_bounds__(512) void k_bscan(const int* __restrict__ bucketCount, int NB, int E,
                                               int* __restrict__ bucketBase,
                                               int* __restrict__ bucketCursor,
                                               int* __restrict__ row_ptr, int N) {
    __shared__ int lds[512];
    int t = threadIdx.x;
    int v = (t < NB) ? bucketCount[t] : 0;
    lds[t] = v;
    __syncthreads();
    for (int off = 1; off < 512; off <<= 1) {
        int u = (t >= off) ? lds[t - off] : 0;
        __syncthreads();
        lds[t] += u;
        __syncthreads();
    }
    if (t < NB) {
        int b = lds[t] - v;
        bucketBase[t] = b;
        bucketCursor[t] = b;
    }
    if (t == 0) row_ptr[N] = E;
}

__global__ __launch_bounds__(256) void k_bucketize(const int* __restrict__ src,
                                                   const int* __restrict__ dst, int E, int NB,
                                                   int* __restrict__ bucketCursor,
                                                   uint_t* __restrict__ bebuf) {
    __shared__ int hist[512];
    __shared__ int base[512];
    int t = threadIdx.x;
    for (int b = t; b < NB; b += 256) hist[b] = 0;
    __syncthreads();
    int per = (E + gridDim.x - 1) / gridDim.x;
    int beg = blockIdx.x * per, end = min(beg + per, E);
    for (int i = beg + t; i < end; i += 256)
        atomicAdd(&hist[dst[i] >> BSHIFT], 1);
    __syncthreads();
    for (int b = t; b < NB; b += 256) {
        int v = hist[b];
        base[b] = v ? atomicAdd(&bucketCursor[b], v) : 0;
        hist[b] = 0;
    }
    __syncthreads();
    for (int i = beg + t; i < end; i += 256) {
        int d = dst[i], s = src[i];
        int b = d >> BSHIFT;
        int off = atomicAdd(&hist[b], 1);
        bebuf[base[b] + off] = ((uint_t)(d & (BNODES - 1)) << 24) | (uint_t)s;
    }
}

__global__ __launch_bounds__(256) void k_bcsr(const uint_t* __restrict__ bebuf,
                                              const int* __restrict__ bucketBase,
                                              const int* __restrict__ bucketCount, int N,
                                              int* __restrict__ row_ptr, int* __restrict__ csr) {
    __shared__ int hist[BNODES];
    __shared__ int cur[BNODES];
    int t = threadIdx.x;
    int b = blockIdx.x;
    int ebase = bucketBase[b], cnt = bucketCount[b];
    int nodeBase = b << BSHIFT;
    hist[t] = 0;
    __syncthreads();
    for (int i = t; i < cnt; i += 256)
        atomicAdd(&hist[bebuf[ebase + i] >> 24], 1);
    __syncthreads();
    int v = hist[t];
    for (int off = 1; off < 256; off <<= 1) {
        int u = (t >= off) ? hist[t - off] : 0;
        __syncthreads();
        hist[t] += u;
        __syncthreads();
    }
    int excl = hist[t] - v;
    int node = nodeBase + t;
    if (node < N) row_ptr[node] = ebase + excl;
    cur[t] = excl;
    __syncthreads();
    for (int i = t; i < cnt; i += 256) {
        uint_t e = bebuf[ebase + i];
        int dl = (int)(e >> 24);
        int pos = atomicAdd(&cur[dl], 1);
        csr[ebase + pos] = (int)(e & 0xFFFFFFu);
    }
}

// ---------- degree-sorted node permutation (kills wave divergence in k_agg) ----------

__global__ __launch_bounds__(256) void k_dhist(const int* __restrict__ rp, int N,
                                               int* __restrict__ degCount) {
    __shared__ int h[256];
    int t = threadIdx.x;
    h[t] = 0;
    __syncthreads();
    int i = blockIdx.x * 256 + t;
    if (i < N) {
        int d = rp[i + 1] - rp[i];
        atomicAdd(&h[d > 255 ? 255 : d], 1);
    }
    __syncthreads();
    int v = h[t];
    if (v) atomicAdd(&degCount[t], v);
}

__global__ __launch_bounds__(256) void k_dscan(const int* __restrict__ degCount,
                                               int* __restrict__ classBase,
                                               int* __restrict__ classCursor) {
    __shared__ int lds[256];
    int t = threadIdx.x;
    int v = degCount[t];
    lds[t] = v;
    __syncthreads();
    for (int off = 1; off < 256; off <<= 1) {
        int u = (t >= off) ? lds[t - off] : 0;
        __syncthreads();
        lds[t] += u;
        __syncthreads();
    }
    int b = lds[t] - v;
    classBase[t] = b;
    classCursor[t] = b;
}

__global__ __launch_bounds__(256) void k_dscatter(const int* __restrict__ rp, int N,
                                                  int* __restrict__ classCursor,
                                                  int* __restrict__ perm) {
    __shared__ int h[256];
    __shared__ int base[256];
    int t = threadIdx.x;
    h[t] = 0;
    __syncthreads();
    int i = blockIdx.x * 256 + t;
    int cls = 0;
    if (i < N) {
        int d = rp[i + 1] - rp[i];
        cls = d > 255 ? 255 : d;
        atomicAdd(&h[cls], 1);
    }
    __syncthreads();
    int v = h[t];
    base[t] = v ? atomicAdd(&classCursor[t], v) : 0;
    h[t] = 0;
    __syncthreads();
    if (i < N) {
        int r = atomicAdd(&h[cls], 1);
        perm[base[cls] + r] = i;
    }
}

// ---------- mean aggregation: 16 lanes/node, degree-sorted perm, x8 unroll ----------
// Row-major 256 B rows: gather granule == 2 cache lines, fetch-optimal (R6
// showed 32 B granules over-fetch 2x). Perm puts ~equal-degree nodes in each
// wave so the 4 node-groups' edge loops stay in lockstep.

__device__ __forceinline__ void acc8(float* a, uint4 p) {
    a[0] += bf2f((ushort_t)(p.x & 0xffffu));
    a[1] += bf2f((ushort_t)(p.x >> 16));
    a[2] += bf2f((ushort_t)(p.y & 0xffffu));
    a[3] += bf2f((ushort_t)(p.y >> 16));
    a[4] += bf2f((ushort_t)(p.z & 0xffffu));
    a[5] += bf2f((ushort_t)(p.z >> 16));
    a[6] += bf2f((ushort_t)(p.w & 0xffffu));
    a[7] += bf2f((ushort_t)(p.w >> 16));
}

__global__ __launch_bounds__(256) void k_agg(const ushort_t* __restrict__ X,
                                             const int* __restrict__ row_ptr,
                                             const int* __restrict__ csr,
                                             const int* __restrict__ perm,
                                             ushort_t* __restrict__ out, int n) {
    int idx = (int)((blockIdx.x * (unsigned)blockDim.x + threadIdx.x) >> 4);
    if (idx >= n) return;
    int node = perm[idx];
    int sl = threadIdx.x & 15;               // sub-lane: 8 bf16 = 16 B of the row
    int beg = row_ptr[node], end = row_ptr[node + 1];
    float a[8] = {0.f, 0.f, 0.f, 0.f, 0.f, 0.f, 0.f, 0.f};

    int e = beg;
    for (; e + 8 <= end; e += 8) {
        int s0 = csr[e + 0], s1 = csr[e + 1], s2 = csr[e + 2], s3 = csr[e + 3];
        int s4 = csr[e + 4], s5 = csr[e + 5], s6 = csr[e + 6], s7 = csr[e + 7];
        uint4 p0 = *(const uint4*)(X + (size_t)s0 * DIM + sl * 8);
        uint4 p1 = *(const uint4*)(X + (size_t)s1 * DIM + sl * 8);
        uint4 p2 = *(const uint4*)(X + (size_t)s2 * DIM + sl * 8);
        uint4 p3 = *(const uint4*)(X + (size_t)s3 * DIM + sl * 8);
        uint4 p4 = *(const uint4*)(X + (size_t)s4 * DIM + sl * 8);
        uint4 p5 = *(const uint4*)(X + (size_t)s5 * DIM + sl * 8);
        uint4 p6 = *(const uint4*)(X + (size_t)s6 * DIM + sl * 8);
        uint4 p7 = *(const uint4*)(X + (size_t)s7 * DIM + sl * 8);
        acc8(a, p0); acc8(a, p1); acc8(a, p2); acc8(a, p3);
        acc8(a, p4); acc8(a, p5); acc8(a, p6); acc8(a, p7);
    }
    for (; e + 4 <= end; e += 4) {
        int s0 = csr[e + 0], s1 = csr[e + 1], s2 = csr[e + 2], s3 = csr[e + 3];
        uint4 p0 = *(const uint4*)(X + (size_t)s0 * DIM + sl * 8);
        uint4 p1 = *(const uint4*)(X + (size_t)s1 * DIM + sl * 8);
        uint4 p2 = *(const uint4*)(X + (size_t)s2 * DIM + sl * 8);
        uint4 p3 = *(const uint4*)(X + (size_t)s3 * DIM + sl * 8);
        acc8(a, p0); acc8(a, p1); acc8(a, p2); acc8(a, p3);
    }
    for (; e < end; e++) {
        int s = csr[e];
        uint4 p = *(const uint4*)(X + (size_t)s * DIM + sl * 8);
        acc8(a, p);
    }

    int cnt = end - beg;
    float sc = (cnt > 0) ? 1.f / (float)cnt : 0.f;
    uint4 o;
    o.x = (uint_t)f2bf(a[0] * sc) | ((uint_t)f2bf(a[1] * sc) << 16);
    o.y = (uint_t)f2bf(a[2] * sc) | ((uint_t)f2bf(a[3] * sc) << 16);
    o.z = (uint_t)f2bf(a[4] * sc) | ((uint_t)f2bf(a[5] * sc) << 16);
    o.w = (uint_t)f2bf(a[6] * sc) | ((uint_t)f2bf(a[7] * sc) << 16);
    *(uint4*)(out + (size_t)node * DIM + sl * 8) = o;
}

// ---------- fused GEMM with LDS-staged weights ----------
// out = A1*W_l + A2*W_r + b; 32 rows/wave, 128 rows/block (4 waves).
// Both WT tables (64 KB) staged once per block, XOR-swizzled at 16 B-chunk
// granularity so ds_read_b128 fragment reads are <=2-way bank-aliased.
// MFMA 16x16x32 bf16 layouts (m89-verified):
//   A frag: lane holds A[m=lane&15][k=quad*8+j]
//   B frag: lane holds B[k=quad*8+j][n=lane&15] = WT[n=lane&15][k=quad*8+j]
//   C/D   : col=lane&15, row=quad*4+reg

template <bool RELU, bool OUT_BF16>
__global__ __launch_bounds__(256) void k_gemm(const ushort_t* __restrict__ A1,
                                              const ushort_t* __restrict__ A2,
                                              const ushort_t* __restrict__ WTl,
                                              const ushort_t* __restrict__ WTr,
                                              const float* __restrict__ bias,
                                              void* __restrict__ Out, int n_waves, int M) {
    __shared__ ushort_t sW[2 * 128 * 128];   // 64 KB
    int t = threadIdx.x;
    int wave = (int)((blockIdx.x * 256u + t) >> 6);
    int lane = t & 63;
    int col = lane & 15;
    int quad = lane >> 4;
    bool active = (wave < n_waves);

    // A-fragment loads issued first: their latency overlaps staging + barrier.
    bf16x8 a[2][8];
    if (active) {
#pragma unroll
        for (int tt = 0; tt < 2; tt++) {
            int arow = wave * 32 + tt * 16 + col;
            const ushort_t* a1p = A1 + (size_t)arow * DIM + quad * 8;
            const ushort_t* a2p = A2 + (size_t)arow * DIM + quad * 8;
#pragma unroll
            for (int ks = 0; ks < 4; ks++) a[tt][ks] = *(const bf16x8*)(a1p + ks * 32);
#pragma unroll
            for (int ks = 0; ks < 4; ks++) a[tt][4 + ks] = *(const bf16x8*)(a2p + ks * 32);
        }
    }

    // stage weights: thread t copies one row (t>>7 selects table, t&127 the row)
    {
        int tab = t >> 7, row = t & 127;
        const ushort_t* g = (tab ? WTr : WTl) + (size_t)row * 128;
        ushort_t* d = sW + (size_t)t * 128;
        int sw = row & 15;
#pragma unroll
        for (int c = 0; c < 16; c++) {
            uint4 v = *(const uint4*)(g + c * 8);
            *(uint4*)(d + ((c ^ sw) * 8)) = v;
        }
    }
    __syncthreads();
    if (!active) return;

    f32x4 acc[2][8];
#pragma unroll
    for (int tt = 0; tt < 2; tt++)
#pragma unroll
        for (int nt = 0; nt < 8; nt++) acc[tt][nt] = (f32x4){0.f, 0.f, 0.f, 0.f};

    const ushort_t* sWl = sW;
    const ushort_t* sWr = sW + 128 * 128;
#pragma unroll
    for (int nt = 0; nt < 8; nt++) {
        int row = nt * 16 + col;
        const ushort_t* bl = sWl + (size_t)row * 128;
        const ushort_t* br = sWr + (size_t)row * 128;
#pragma unroll
        for (int ks = 0; ks < 4; ks++) {
            bf16x8 b = *(const bf16x8*)(bl + (((ks * 4 + quad) ^ col) * 8));
            acc[0][nt] = __builtin_amdgcn_mfma_f32_16x16x32_bf16(a[0][ks], b, acc[0][nt], 0, 0, 0);
            acc[1][nt] = __builtin_amdgcn_mfma_f32_16x16x32_bf16(a[1][ks], b, acc[1][nt], 0, 0, 0);
        }
#pragma unroll
        for (int ks = 0; ks < 4; ks++) {
            bf16x8 b = *(const bf16x8*)(br + (((ks * 4 + quad) ^ col) * 8));
            acc[0][nt] = __builtin_amdgcn_mfma_f32_16x16x32_bf16(a[0][4 + ks], b, acc[0][nt], 0, 0, 0);
            acc[1][nt] = __builtin_amdgcn_mfma_f32_16x16x32_bf16(a[1][4 + ks], b, acc[1][nt], 0, 0, 0);
        }
    }

#pragma unroll
    for (int tt = 0; tt < 2; tt++)
#pragma unroll
        for (int nt = 0; nt < 8; nt++) {
            int c = nt * 16 + col;
            float bv = bias[c];
#pragma unroll
            for (int r = 0; r < 4; r++) {
                int m = wave * 32 + tt * 16 + quad * 4 + r;
                if (m < M) {
                    float v = acc[tt][nt][r] + bv;
                    if (RELU) v = v > 0.f ? v : 0.f;
                    if (OUT_BF16)
                        ((ushort_t*)Out)[(size_t)m * DIM + c] = f2bf(v);
                    else
                        ((float*)Out)[(size_t)m * DIM + c] = v;
                }
            }
        }
}

// ---------- host ----------

extern "C" void kernel_launch(void* const* d_in, const int* in_sizes, int n_in,
                              void* d_out, int out_size, void* d_ws, size_t ws_size,
                              hipStream_t stream) {
    const int N = in_sizes[0] / DIM;   // 100000
    const int E = in_sizes[1] / 2;     // 1600000
    const int NB = (N + BNODES - 1) >> BSHIFT;   // 391 buckets

    const float* x   = (const float*)d_in[0];
    const int*   ei  = (const int*)d_in[1];
    const int*   src = ei;
    const int*   dst = ei + E;
    const float* W1l = (const float*)d_in[2];
    const float* b1  = (const float*)d_in[3];
    const float* W1r = (const float*)d_in[4];
    const float* W2l = (const float*)d_in[5];
    const float* b2  = (const float*)d_in[6];
    const float* W2r = (const float*)d_in[7];
    float* out = (float*)d_out;

    char* ws = (char*)d_ws;
    size_t off = 0;
    auto alloc = [&](size_t bytes) -> char* {
        char* p = ws + off;
        off = (off + bytes + 255) & ~(size_t)255;
        return p;
    };

    int*      bucketCount  = (int*)alloc((size_t)NB * 4);
    int*      bucketBase   = (int*)alloc((size_t)NB * 4);
    int*      bucketCursor = (int*)alloc((size_t)NB * 4);
    int*      degCount     = (int*)alloc(256 * 4);
    int*      classBase    = (int*)alloc(256 * 4);
    int*      classCursor  = (int*)alloc(256 * 4);
    int*      perm         = (int*)alloc((size_t)N * 4);
    int*      row_ptr      = (int*)alloc((size_t)(N + 1) * 4);
    int*      csr          = (int*)alloc((size_t)E * 4);
    uint_t*   bebuf        = (uint_t*)alloc((size_t)E * 4);
    size_t    fpad         = (size_t)32 * DIM * 2;   // tile-padding for MFMA A loads
    ushort_t* xb           = (ushort_t*)alloc((size_t)N * DIM * 2 + fpad);
    ushort_t* hb           = (ushort_t*)alloc((size_t)N * DIM * 2 + fpad);
    ushort_t* aggb         = (ushort_t*)alloc((size_t)N * DIM * 2 + fpad);
    ushort_t* wt1l         = (ushort_t*)alloc((size_t)DIM * DIM * 2);
    ushort_t* wt1r         = (ushort_t*)alloc((size_t)DIM * DIM * 2);
    ushort_t* wt2l         = (ushort_t*)alloc((size_t)DIM * DIM * 2);
    ushort_t* wt2r         = (ushort_t*)alloc((size_t)DIM * DIM * 2);

    // zero histograms (ws is poisoned each call)
    hipMemsetAsync(bucketCount, 0, (size_t)NB * 4, stream);
    hipMemsetAsync(degCount, 0, 256 * 4, stream);

    // x -> bf16 (row-major)
    {
        int n4 = N * DIM / 4;
        k_cvt_f32_bf16<<<dim3((n4 + 255) / 256), dim3(256), 0, stream>>>(x, xb, n4);
    }
    // weights -> transposed bf16 (single launch)
    k_wt4<<<dim3(4 * DIM * DIM / 256), dim3(256), 0, stream>>>(W1l, W1r, W2l, W2r,
                                                               wt1l, wt1r, wt2l, wt2r);
    // CSR build: bucket counting sort
    k_bhist<<<dim3(256), dim3(256), 0, stream>>>(dst, E, NB, bucketCount);
    k_bscan<<<dim3(1), dim3(512), 0, stream>>>(bucketCount, NB, E, bucketBase, bucketCursor, row_ptr, N);
    k_bucketize<<<dim3(256), dim3(256), 0, stream>>>(src, dst, E, NB, bucketCursor, bebuf);
    k_bcsr<<<dim3(NB), dim3(256), 0, stream>>>(bebuf, bucketBase, bucketCount, N, row_ptr, csr);
    // degree-sorted permutation
    {
        int nblk = (N + 255) / 256;
        k_dhist<<<dim3(nblk), dim3(256), 0, stream>>>(row_ptr, N, degCount);
        k_dscan<<<dim3(1), dim3(256), 0, stream>>>(degCount, classBase, classCursor);
        k_dscatter<<<dim3(nblk), dim3(256), 0, stream>>>(row_ptr, N, classCursor, perm);
    }

    const int n_waves = (N + 31) / 32;                          // 3125 (32 rows/wave)
    dim3 gemm_grid((n_waves + 3) / 4), gemm_blk(256);
    dim3 agg_grid((N + 15) / 16), agg_blk(256);                 // 16 nodes/block (16 lanes/node)

    // layer 1
    k_agg<<<agg_grid, agg_blk, 0, stream>>>(xb, row_ptr, csr, perm, aggb, N);
    k_gemm<true, true><<<gemm_grid, gemm_blk, 0, stream>>>(aggb, xb, wt1l, wt1r, b1, hb, n_waves, N);
    // layer 2
    k_agg<<<agg_grid, agg_blk, 0, stream>>>(hb, row_ptr, csr, perm, aggb, N);
    k_gemm<false, false><<<gemm_grid, gemm_blk, 0, stream>>>(aggb, hb, wt2l, wt2r, b2, out, n_waves, N);

    (void)n_in; (void)out_size; (void)ws_size;
}

// Round 8
// 364.305 us; speedup vs baseline: 1.6037x; 1.0321x over previous
//
#include <hip/hip_runtime.h>

typedef unsigned short ushort_t;
typedef unsigned int uint_t;

typedef short bf16x8 __attribute__((ext_vector_type(8)));
typedef float f32x4 __attribute__((ext_vector_type(4)));

#define DIM 128
#define BSHIFT 8
#define BNODES 256           // nodes per bucket (1<<BSHIFT)

__device__ __forceinline__ float bf2f(ushort_t u) {
    uint_t x = ((uint_t)u) << 16;
    float f;
    __builtin_memcpy(&f, &x, 4);
    return f;
}

__device__ __forceinline__ ushort_t f2bf(float f) {
    uint_t x;
    __builtin_memcpy(&x, &f, 4);
    uint_t r = (x + 0x7fffu + ((x >> 16) & 1u)) >> 16;
    return (ushort_t)r;
}

// ---------- conversion kernels ----------

__global__ void k_cvt_f32_bf16(const float* __restrict__ in, ushort_t* __restrict__ out, int n4) {
    int i = blockIdx.x * blockDim.x + threadIdx.x;
    if (i < n4) {
        float4 f = ((const float4*)in)[i];
        ushort4 u;
        u.x = f2bf(f.x); u.y = f2bf(f.y); u.z = f2bf(f.z); u.w = f2bf(f.w);
        ((ushort4*)out)[i] = u;
    }
}

// all four weight transposes in one launch: WT[n*128+k] = bf16(W[k*128+n])
__global__ void k_wt4(const float* __restrict__ W0, const float* __restrict__ W1,
                      const float* __restrict__ W2, const float* __restrict__ W3,
                      ushort_t* __restrict__ T0, ushort_t* __restrict__ T1,
                      ushort_t* __restrict__ T2, ushort_t* __restrict__ T3) {
    int i = blockIdx.x * blockDim.x + threadIdx.x;  // 4*16384
    int w = i >> 14, j = i & 16383;
    int n = j >> 7, k = j & 127;
    const float* W = (w == 0) ? W0 : (w == 1) ? W1 : (w == 2) ? W2 : W3;
    ushort_t* T = (w == 0) ? T0 : (w == 1) ? T1 : (w == 2) ? T2 : T3;
    T[j] = f2bf(W[k * DIM + n]);
}

// ---------- CSR build via two-level bucket counting sort ----------
// Device-scope atomics execute at the coherence point on 8-XCD parts and cap
// at ~13 G ops/s; LDS histograms + ~0.2M global reservations avoid that tax.

__global__ __launch_bounds__(256) void k_bhist(const int* __restrict__ dst, int E, int NB,
                                               int* __restrict__ bucketCount) {
    __shared__ int hist[512];
    int t = threadIdx.x;
    for (int b = t; b < NB; b += 256) hist[b] = 0;
    __syncthreads();
    int per = (E + gridDim.x - 1) / gridDim.x;
    int beg = blockIdx.x * per, end = min(beg + per, E);
    for (int i = beg + t; i < end; i += 256)
        atomicAdd(&hist[dst[i] >> BSHIFT], 1);
    __syncthreads();
    for (int b = t; b < NB; b += 256) {
        int v = hist[b];
        if (v) atomicAdd(&bucketCount[b], v);
    }
}

__global__ __launch_bounds__(512) void k_bscan(const int* __restrict__ bucketCount, int NB, int E,
                                               int* __restrict__ bucketBase,
                                               int* __restrict__ bucketCursor,
                                               int* __restrict__ row_ptr, int N) {
    __shared__ int lds[512];
    int t = threadIdx.x;
    int v = (t < NB) ? bucketCount[t] : 0;
    lds[t] = v;
    __syncthreads();
    for (int off = 1; off < 512; off <<= 1) {
        int u = (t >= off) ? lds[t - off] : 0;
        __syncthreads();
        lds[t] += u;
        __syncthreads();
    }
    if (t < NB) {
        int b = lds[t] - v;
        bucketBase[t] = b;
        bucketCursor[t] = b;
    }
    if (t == 0) row_ptr[N] = E;
}

__global__ __launch_bounds__(256) void k_bucketize(const int* __restrict__ src,
                                                   const int* __restrict__ dst, int E, int NB,
                                                   int* __restrict__ bucketCursor,
                                                   uint_t* __restrict__ bebuf) {
    __shared__ int hist[512];
    __shared__ int base[512];
    int t = threadIdx.x;
    for (int b = t; b < NB; b += 256) hist[b] = 0;
    __syncthreads();
    int per = (E + gridDim.x - 1) / gridDim.x;
    int beg = blockIdx.x * per, end = min(beg + per, E);
    for (int i = beg + t; i < end; i += 256)
        atomicAdd(&hist[dst[i] >> BSHIFT], 1);
    __syncthreads();
    for (int b = t; b < NB; b += 256) {
        int v = hist[b];
        base[b] = v ? atomicAdd(&bucketCursor[b], v) : 0;
        hist[b] = 0;
    }
    __syncthreads();
    for (int i = beg + t; i < end; i += 256) {
        int d = dst[i], s = src[i];
        int b = d >> BSHIFT;
        int off = atomicAdd(&hist[b], 1);
        bebuf[base[b] + off] = ((uint_t)(d & (BNODES - 1)) << 24) | (uint_t)s;
    }
}

__global__ __launch_bounds__(256) void k_bcsr(const uint_t* __restrict__ bebuf,
                                              const int* __restrict__ bucketBase,
                                              const int* __restrict__ bucketCount, int N,
                                              int* __restrict__ row_ptr, int* __restrict__ csr) {
    __shared__ int hist[BNODES];
    __shared__ int cur[BNODES];
    int t = threadIdx.x;
    int b = blockIdx.x;
    int ebase = bucketBase[b], cnt = bucketCount[b];
    int nodeBase = b << BSHIFT;
    hist[t] = 0;
    __syncthreads();
    for (int i = t; i < cnt; i += 256)
        atomicAdd(&hist[bebuf[ebase + i] >> 24], 1);
    __syncthreads();
    int v = hist[t];
    for (int off = 1; off < 256; off <<= 1) {
        int u = (t >= off) ? hist[t - off] : 0;
        __syncthreads();
        hist[t] += u;
        __syncthreads();
    }
    int excl = hist[t] - v;
    int node = nodeBase + t;
    if (node < N) row_ptr[node] = ebase + excl;
    cur[t] = excl;
    __syncthreads();
    for (int i = t; i < cnt; i += 256) {
        uint_t e = bebuf[ebase + i];
        int dl = (int)(e >> 24);
        int pos = atomicAdd(&cur[dl], 1);
        csr[ebase + pos] = (int)(e & 0xFFFFFFu);
    }
}

// ---------- fused SAGE layer: mean-gather + dual-K GEMM + bias (+ReLU) ----------
// One block = 16 nodes = one 16-row M-tile. N = 100000 = 6250 blocks * 16 exact.
// Phase 1 (R5-proven gather): 16 lanes/node, 16 B/lane/row, x4 edge unroll;
// fp32 accumulate, mean, pack bf16 -> swizzled LDS row. Root row also staged.
// Phase 2: 4 waves x 2 N-columns; B-frags preloaded from L2-hot WT tables at
// kernel start (overlaps gather); 16 MFMA/wave; fused epilogue.
// LDS swizzle: 16 B chunk c of row r stored at chunk (c ^ r) -> ds_read_b128
// A-frag reads are <=2-way bank-aliased (free).
// MFMA 16x16x32 bf16 layouts (m89-verified):
//   A frag: lane holds A[m=lane&15][k=quad*8+j]  (chunk c = ks*4+quad)
//   B frag: lane holds B[k=quad*8+j][n=lane&15] = WT[n][ks*32+quad*8+j]
//   C/D   : col=lane&15, row=quad*4+reg

__device__ __forceinline__ void acc8(float* a, uint4 p) {
    a[0] += bf2f((ushort_t)(p.x & 0xffffu));
    a[1] += bf2f((ushort_t)(p.x >> 16));
    a[2] += bf2f((ushort_t)(p.y & 0xffffu));
    a[3] += bf2f((ushort_t)(p.y >> 16));
    a[4] += bf2f((ushort_t)(p.z & 0xffffu));
    a[5] += bf2f((ushort_t)(p.z >> 16));
    a[6] += bf2f((ushort_t)(p.w & 0xffffu));
    a[7] += bf2f((ushort_t)(p.w >> 16));
}

template <bool RELU, bool OUT_BF16>
__global__ __launch_bounds__(256) void k_fused(const ushort_t* __restrict__ X,
                                               const int* __restrict__ row_ptr,
                                               const int* __restrict__ csr,
                                               const ushort_t* __restrict__ WTl,
                                               const ushort_t* __restrict__ WTr,
                                               const float* __restrict__ bias,
                                               void* __restrict__ Out) {
    __shared__ ushort_t sA[16 * 128];   // agg rows (bf16, swizzled)  4 KB
    __shared__ ushort_t sR[16 * 128];   // root rows (bf16, swizzled) 4 KB
    int t = threadIdx.x;
    int nodeLocal = t >> 4, sl = t & 15;
    int g = blockIdx.x * 16 + nodeLocal;      // grid is exact: N % 16 == 0
    int lane = t & 63, w = t >> 6;
    int quad = lane >> 4, ncol = lane & 15;

    // ---- B-fragment preload (independent of gather; L2-hot 64 KB tables) ----
    bf16x8 bAgg[2][4], bRoot[2][4];
#pragma unroll
    for (int j = 0; j < 2; j++) {
        int nt = w * 2 + j;
        const ushort_t* bl = WTl + (size_t)(nt * 16 + ncol) * 128 + quad * 8;
        const ushort_t* br = WTr + (size_t)(nt * 16 + ncol) * 128 + quad * 8;
#pragma unroll
        for (int ks = 0; ks < 4; ks++) {
            bAgg[j][ks] = *(const bf16x8*)(bl + ks * 32);
            bRoot[j][ks] = *(const bf16x8*)(br + ks * 32);
        }
    }

    // ---- root row -> LDS (swizzled) ----
    {
        uint4 rv = *(const uint4*)(X + (size_t)g * DIM + sl * 8);
        *(uint4*)(sR + nodeLocal * 128 + ((sl ^ nodeLocal) * 8)) = rv;
    }

    // ---- phase 1: mean gather (R5 structure) ----
    {
        int beg = row_ptr[g], end = row_ptr[g + 1];
        float a[8] = {0.f, 0.f, 0.f, 0.f, 0.f, 0.f, 0.f, 0.f};
        int e = beg;
        for (; e + 4 <= end; e += 4) {
            int s0 = csr[e + 0], s1 = csr[e + 1], s2 = csr[e + 2], s3 = csr[e + 3];
            uint4 p0 = *(const uint4*)(X + (size_t)s0 * DIM + sl * 8);
            uint4 p1 = *(const uint4*)(X + (size_t)s1 * DIM + sl * 8);
            uint4 p2 = *(const uint4*)(X + (size_t)s2 * DIM + sl * 8);
            uint4 p3 = *(const uint4*)(X + (size_t)s3 * DIM + sl * 8);
            acc8(a, p0); acc8(a, p1); acc8(a, p2); acc8(a, p3);
        }
        for (; e < end; e++) {
            int s = csr[e];
            uint4 p = *(const uint4*)(X + (size_t)s * DIM + sl * 8);
            acc8(a, p);
        }
        int cnt = end - beg;
        float sc = (cnt > 0) ? 1.f / (float)cnt : 0.f;
        uint4 o;
        o.x = (uint_t)f2bf(a[0] * sc) | ((uint_t)f2bf(a[1] * sc) << 16);
        o.y = (uint_t)f2bf(a[2] * sc) | ((uint_t)f2bf(a[3] * sc) << 16);
        o.z = (uint_t)f2bf(a[4] * sc) | ((uint_t)f2bf(a[5] * sc) << 16);
        o.w = (uint_t)f2bf(a[6] * sc) | ((uint_t)f2bf(a[7] * sc) << 16);
        *(uint4*)(sA + nodeLocal * 128 + ((sl ^ nodeLocal) * 8)) = o;
    }
    __syncthreads();

    // ---- phase 2: 16-row GEMM tile, this wave covers N-cols [w*32, w*32+32) ----
    f32x4 acc[2];
    acc[0] = (f32x4){0.f, 0.f, 0.f, 0.f};
    acc[1] = (f32x4){0.f, 0.f, 0.f, 0.f};
#pragma unroll
    for (int ks = 0; ks < 4; ks++) {
        int c = ks * 4 + quad;
        bf16x8 aAgg = *(const bf16x8*)(sA + ncol * 128 + ((c ^ ncol) * 8));
        bf16x8 aRoot = *(const bf16x8*)(sR + ncol * 128 + ((c ^ ncol) * 8));
#pragma unroll
        for (int j = 0; j < 2; j++) {
            acc[j] = __builtin_amdgcn_mfma_f32_16x16x32_bf16(aAgg, bAgg[j][ks], acc[j], 0, 0, 0);
            acc[j] = __builtin_amdgcn_mfma_f32_16x16x32_bf16(aRoot, bRoot[j][ks], acc[j], 0, 0, 0);
        }
    }

    // ---- epilogue ----
#pragma unroll
    for (int j = 0; j < 2; j++) {
        int col = (w * 2 + j) * 16 + ncol;
        float bv = bias[col];
#pragma unroll
        for (int r = 0; r < 4; r++) {
            int gm = blockIdx.x * 16 + quad * 4 + r;
            float v = acc[j][r] + bv;
            if (RELU) v = v > 0.f ? v : 0.f;
            if (OUT_BF16)
                ((ushort_t*)Out)[(size_t)gm * DIM + col] = f2bf(v);
            else
                ((float*)Out)[(size_t)gm * DIM + col] = v;
        }
    }
}

// ---------- host ----------

extern "C" void kernel_launch(void* const* d_in, const int* in_sizes, int n_in,
                              void* d_out, int out_size, void* d_ws, size_t ws_size,
                              hipStream_t stream) {
    const int N = in_sizes[0] / DIM;   // 100000 (N % 16 == 0)
    const int E = in_sizes[1] / 2;     // 1600000
    const int NB = (N + BNODES - 1) >> BSHIFT;   // 391 buckets

    const float* x   = (const float*)d_in[0];
    const int*   ei  = (const int*)d_in[1];
    const int*   src = ei;
    const int*   dst = ei + E;
    const float* W1l = (const float*)d_in[2];
    const float* b1  = (const float*)d_in[3];
    const float* W1r = (const float*)d_in[4];
    const float* W2l = (const float*)d_in[5];
    const float* b2  = (const float*)d_in[6];
    const float* W2r = (const float*)d_in[7];
    float* out = (float*)d_out;

    char* ws = (char*)d_ws;
    size_t off = 0;
    auto alloc = [&](size_t bytes) -> char* {
        char* p = ws + off;
        off = (off + bytes + 255) & ~(size_t)255;
        return p;
    };

    int*      bucketCount  = (int*)alloc((size_t)NB * 4);
    int*      bucketBase   = (int*)alloc((size_t)NB * 4);
    int*      bucketCursor = (int*)alloc((size_t)NB * 4);
    int*      row_ptr      = (int*)alloc((size_t)(N + 1) * 4);
    int*      csr          = (int*)alloc((size_t)E * 4);
    uint_t*   bebuf        = (uint_t*)alloc((size_t)E * 4);
    ushort_t* xb           = (ushort_t*)alloc((size_t)N * DIM * 2);
    ushort_t* hb           = (ushort_t*)alloc((size_t)N * DIM * 2);
    ushort_t* wt1l         = (ushort_t*)alloc((size_t)DIM * DIM * 2);
    ushort_t* wt1r         = (ushort_t*)alloc((size_t)DIM * DIM * 2);
    ushort_t* wt2l         = (ushort_t*)alloc((size_t)DIM * DIM * 2);
    ushort_t* wt2r         = (ushort_t*)alloc((size_t)DIM * DIM * 2);

    // zero bucket histogram (ws is poisoned each call)
    hipMemsetAsync(bucketCount, 0, (size_t)NB * 4, stream);

    // x -> bf16 (row-major)
    {
        int n4 = N * DIM / 4;
        k_cvt_f32_bf16<<<dim3((n4 + 255) / 256), dim3(256), 0, stream>>>(x, xb, n4);
    }
    // weights -> transposed bf16 (single launch)
    k_wt4<<<dim3(4 * DIM * DIM / 256), dim3(256), 0, stream>>>(W1l, W1r, W2l, W2r,
                                                               wt1l, wt1r, wt2l, wt2r);
    // CSR build: bucket counting sort
    k_bhist<<<dim3(256), dim3(256), 0, stream>>>(dst, E, NB, bucketCount);
    k_bscan<<<dim3(1), dim3(512), 0, stream>>>(bucketCount, NB, E, bucketBase, bucketCursor, row_ptr, N);
    k_bucketize<<<dim3(256), dim3(256), 0, stream>>>(src, dst, E, NB, bucketCursor, bebuf);
    k_bcsr<<<dim3(NB), dim3(256), 0, stream>>>(bebuf, bucketBase, bucketCount, N, row_ptr, csr);

    // fused layers: one block per 16-node M-tile
    dim3 fgrid(N / 16), fblk(256);
    k_fused<true, true><<<fgrid, fblk, 0, stream>>>(xb, row_ptr, csr, wt1l, wt1r, b1, hb);
    k_fused<false, false><<<fgrid, fblk, 0, stream>>>(hb, row_ptr, csr, wt2l, wt2r, b2, out);

    (void)n_in; (void)out_size; (void)ws_size;
}